// Round 1
// baseline (337.680 us; speedup 1.0000x reference)
//
#include <hip/hip_runtime.h>
#include <hip/hip_bf16.h>

#define NROWS 8192
#define SD 512
#define FDIM 128
#define KNN 10
#define C_CONST 1.0e-3f
#define L_CONST 5.0f
#define EPS_CONST 1.0e-3f
#define BIGF 3.0e38f

typedef float f32x4 __attribute__((ext_vector_type(4)));
typedef __bf16 bf16x8 __attribute__((ext_vector_type(8)));

__device__ __forceinline__ unsigned short f32_to_bf16_rne(float f) {
    unsigned int x = __float_as_uint(f);
    unsigned int lsb = (x >> 16) & 1u;
    x += 0x7fffu + lsb;
    return (unsigned short)(x >> 16);
}

// ---------------- K1: fused 3-MLP (pred, tgt, embed) ----------------
// grid 512 blocks x 384 threads, 16 rows per block (4 batches of 4)
__global__ __launch_bounds__(384) void k_mlp(
    const float* __restrict__ s,
    const float* __restrict__ w1, const float* __restrict__ b1,
    const float* __restrict__ w2, const float* __restrict__ b2,
    const float* __restrict__ w3, const float* __restrict__ b3,
    const float* __restrict__ wt1, const float* __restrict__ bt1,
    const float* __restrict__ wt2, const float* __restrict__ bt2,
    const float* __restrict__ wt3, const float* __restrict__ bt3,
    const float* __restrict__ wz1, const float* __restrict__ bz1,
    const float* __restrict__ wz2, const float* __restrict__ bz2,
    const float* __restrict__ wz3, const float* __restrict__ bz3,
    unsigned short* __restrict__ zb, float* __restrict__ sq,
    float* __restrict__ alpha)
{
    __shared__ float s_lds[4][SD];
    __shared__ float h1[4][384];
    __shared__ float h2[4][192];
    __shared__ float red[4][FDIM];
    __shared__ float pt[4][2];

    const int t = threadIdx.x;
    const int rows0 = blockIdx.x * 16;

    for (int batch = 0; batch < 4; ++batch) {
        const int r0 = rows0 + batch * 4;
        __syncthreads();
        // stage 4 rows of s
        for (int i = t; i < 4 * (SD / 4); i += 384) {
            int r = i / (SD / 4), c = i % (SD / 4);
            ((f32x4*)s_lds[r])[c] = ((const f32x4*)(s + (size_t)(r0 + r) * SD))[c];
        }
        __syncthreads();
        // layer 1: 384 concat outputs (128 pred | 128 tgt | 128 z)
        {
            const float* W; const float* B; int o;
            if (t < 128)      { W = w1  + (size_t)t * SD;         B = b1;  o = t; }
            else if (t < 256) { W = wt1 + (size_t)(t - 128) * SD; B = bt1; o = t - 128; }
            else              { W = wz1 + (size_t)(t - 256) * SD; B = bz1; o = t - 256; }
            float acc[4] = {0.f, 0.f, 0.f, 0.f};
            for (int k = 0; k < SD; k += 4) {
                f32x4 wv = *(const f32x4*)(W + k);
                #pragma unroll
                for (int r = 0; r < 4; ++r) {
                    f32x4 sv = *(const f32x4*)(&s_lds[r][k]);
                    acc[r] += wv.x * sv.x + wv.y * sv.y + wv.z * sv.z + wv.w * sv.w;
                }
            }
            float bb = B[o];
            #pragma unroll
            for (int r = 0; r < 4; ++r) h1[r][t] = fmaxf(acc[r] + bb, 0.f);
        }
        __syncthreads();
        // layer 2: 192 concat outputs (64 pred | 64 tgt | 64 z)
        if (t < 192) {
            const float* W; const float* B; int o; int hoff;
            if (t < 64)       { W = w2  + (size_t)t * 128;         B = b2;  o = t;       hoff = 0; }
            else if (t < 128) { W = wt2 + (size_t)(t - 64) * 128;  B = bt2; o = t - 64;  hoff = 128; }
            else              { W = wz2 + (size_t)(t - 128) * 128; B = bz2; o = t - 128; hoff = 256; }
            float acc[4] = {0.f, 0.f, 0.f, 0.f};
            for (int k = 0; k < 128; k += 4) {
                f32x4 wv = *(const f32x4*)(W + k);
                #pragma unroll
                for (int r = 0; r < 4; ++r) {
                    f32x4 hv = *(const f32x4*)(&h1[r][hoff + k]);
                    acc[r] += wv.x * hv.x + wv.y * hv.y + wv.z * hv.z + wv.w * hv.w;
                }
            }
            float bb = B[o];
            #pragma unroll
            for (int r = 0; r < 4; ++r) h2[r][t] = fmaxf(acc[r] + bb, 0.f);
        }
        __syncthreads();
        // layer 3
        if (t < 128) {
            // z outputs (128), from h2[r][128..191]
            const float* W = wz3 + (size_t)t * 64;
            float acc[4] = {0.f, 0.f, 0.f, 0.f};
            for (int k = 0; k < 64; k += 4) {
                f32x4 wv = *(const f32x4*)(W + k);
                #pragma unroll
                for (int r = 0; r < 4; ++r) {
                    f32x4 hv = *(const f32x4*)(&h2[r][128 + k]);
                    acc[r] += wv.x * hv.x + wv.y * hv.y + wv.z * hv.z + wv.w * hv.w;
                }
            }
            float bb = bz3[t];
            #pragma unroll
            for (int r = 0; r < 4; ++r) {
                float zv = acc[r] + bb;
                unsigned short u = f32_to_bf16_rne(zv);
                zb[(size_t)(r0 + r) * FDIM + t] = u;
                float zr = __uint_as_float(((unsigned int)u) << 16);
                red[r][t] = zr * zr;
            }
        } else if (t < 192) {
            // pred head: wave 2, lane e over h2[r][0..63]
            int e = t - 128;
            float wv = w3[e];
            for (int r = 0; r < 4; ++r) {
                float p = wv * h2[r][e];
                #pragma unroll
                for (int off = 32; off > 0; off >>= 1) p += __shfl_down(p, off);
                if (e == 0) pt[r][0] = p + b3[0];
            }
        } else if (t < 256) {
            // tgt head: wave 3, lane e over h2[r][64..127]
            int e = t - 192;
            float wv = wt3[e];
            for (int r = 0; r < 4; ++r) {
                float p = wv * h2[r][64 + e];
                #pragma unroll
                for (int off = 32; off > 0; off >>= 1) p += __shfl_down(p, off);
                if (e == 0) pt[r][1] = p + bt3[0];
            }
        }
        __syncthreads();
        // reduce sq (128 -> 1 per row) and write alpha
        if (t < 256) {
            int r = t >> 6, c = t & 63;
            float v = red[r][c] + red[r][c + 64];
            #pragma unroll
            for (int off = 32; off > 0; off >>= 1) v += __shfl_down(v, off);
            if (c == 0) {
                sq[r0 + r] = v;
                float d = pt[r][0] - pt[r][1];
                alpha[r0 + r] = d * d;
            }
        }
    }
}

// ---------------- K2: pairwise dist + per-lane top-10 ----------------
// wave handles 32 queries (2 MFMA col-tiles) x 1024 candidates.
// grid 512 blocks x 256 threads = 2048 waves = 256 qgroups x 8 splits.
__global__ __launch_bounds__(256) void k_pairs(
    const unsigned short* __restrict__ zb, const float* __restrict__ sq,
    float* __restrict__ part)
{
    const int lane = threadIdx.x & 63;
    const int wgid = blockIdx.x * 4 + (threadIdx.x >> 6);
    const int qg = wgid >> 3;
    const int split = wgid & 7;
    const int l15 = lane & 15, lg = lane >> 4;

    bf16x8 bq[2][4];
    int qid[2];
    #pragma unroll
    for (int qt = 0; qt < 2; ++qt) {
        qid[qt] = qg * 32 + qt * 16 + l15;
        #pragma unroll
        for (int kk = 0; kk < 4; ++kk)
            bq[qt][kk] = *(const bf16x8*)(zb + (size_t)qid[qt] * FDIM + kk * 32 + lg * 8);
    }
    float vals[2][10];
    #pragma unroll
    for (int qt = 0; qt < 2; ++qt)
        #pragma unroll
        for (int i = 0; i < 10; ++i) vals[qt][i] = BIGF;

    const int c0 = split * 1024;
    for (int tile = 0; tile < 64; ++tile) {
        const int j0 = c0 + tile * 16;
        bf16x8 av[4];
        #pragma unroll
        for (int kk = 0; kk < 4; ++kk)
            av[kk] = *(const bf16x8*)(zb + (size_t)(j0 + l15) * FDIM + kk * 32 + lg * 8);
        f32x4 sqv = *(const f32x4*)(sq + j0 + lg * 4);
        #pragma unroll
        for (int qt = 0; qt < 2; ++qt) {
            f32x4 acc = {0.f, 0.f, 0.f, 0.f};
            #pragma unroll
            for (int kk = 0; kk < 4; ++kk)
                acc = __builtin_amdgcn_mfma_f32_16x16x32_bf16(av[kk], bq[qt][kk], acc, 0, 0, 0);
            #pragma unroll
            for (int r = 0; r < 4; ++r) {
                int j = j0 + lg * 4 + r;
                float v = sqv[r] - 2.0f * acc[r];       // ranking key: dist^2 - sq_i
                if (j == qid[qt]) v = BIGF;             // exclude self
                if (v < vals[qt][9]) {
                    float tv = v;
                    #pragma unroll
                    for (int s2 = 0; s2 < 10; ++s2) {
                        float lo = fminf(vals[qt][s2], tv);
                        tv = fmaxf(vals[qt][s2], tv);
                        vals[qt][s2] = lo;
                    }
                }
            }
        }
    }
    // merge the 4 lane-groups that share a query (lanes l, l^16, l^32, l^48)
    #pragma unroll
    for (int stage = 16; stage <= 32; stage <<= 1) {
        #pragma unroll
        for (int qt = 0; qt < 2; ++qt) {
            float other[10];
            #pragma unroll
            for (int s2 = 0; s2 < 10; ++s2) other[s2] = __shfl_xor(vals[qt][s2], stage, 64);
            #pragma unroll
            for (int s2 = 0; s2 < 10; ++s2) {
                float tv = other[s2];
                if (tv < vals[qt][9]) {
                    #pragma unroll
                    for (int u = 0; u < 10; ++u) {
                        float lo = fminf(vals[qt][u], tv);
                        tv = fmaxf(vals[qt][u], tv);
                        vals[qt][u] = lo;
                    }
                }
            }
        }
    }
    if (lg == 0) {
        #pragma unroll
        for (int qt = 0; qt < 2; ++qt) {
            float* dst = part + ((size_t)split * NROWS + qid[qt]) * KNN;
            #pragma unroll
            for (int s2 = 0; s2 < 10; ++s2) dst[s2] = vals[qt][s2];
        }
    }
}

// ---------------- K3: merge 8 partial lists, sum 10 sqrt dists ----------------
__global__ __launch_bounds__(256) void k_merge(
    const float* __restrict__ part, const float* __restrict__ sq,
    float* __restrict__ sumk, float* __restrict__ total)
{
    const int q = blockIdx.x * 256 + threadIdx.x;
    float vals[10];
    #pragma unroll
    for (int i = 0; i < 10; ++i) vals[i] = BIGF;
    for (int seg = 0; seg < 8; ++seg) {
        const float* p = part + ((size_t)seg * NROWS + q) * KNN;
        #pragma unroll
        for (int i = 0; i < 10; ++i) {
            float tv = p[i];
            if (tv < vals[9]) {
                #pragma unroll
                for (int u = 0; u < 10; ++u) {
                    float lo = fminf(vals[u], tv);
                    tv = fmaxf(vals[u], tv);
                    vals[u] = lo;
                }
            }
        }
    }
    float sqq = sq[q];
    float sum = 0.f;
    #pragma unroll
    for (int i = 0; i < 10; ++i) {
        float raw = sqq + vals[i];
        sum += (raw > 0.f) ? sqrtf(raw) : 0.f;
    }
    sumk[q] = sum;

    // block-level reduce then one atomic per block (for the global mean)
    __shared__ float red[4];
    float bsum = sum;
    #pragma unroll
    for (int off = 32; off > 0; off >>= 1) bsum += __shfl_down(bsum, off);
    if ((threadIdx.x & 63) == 0) red[threadIdx.x >> 6] = bsum;
    __syncthreads();
    if (threadIdx.x == 0) atomicAdd(total, red[0] + red[1] + red[2] + red[3]);
}

// ---------------- K4: finalize ----------------
__global__ __launch_bounds__(256) void k_final(
    const float* __restrict__ sumk, const float* __restrict__ alpha,
    const float* __restrict__ total, float* __restrict__ out)
{
    const int q = blockIdx.x * 256 + threadIdx.x;
    float mean = (*total) * (1.0f / NROWS);
    float m2 = mean * mean;
    float sk = sumk[q];
    float x = (sk * sk) / m2;
    float knn = EPS_CONST / (x + EPS_CONST);
    float rep = 1.0f / (sqrtf(knn) + C_CONST);
    float a = alpha[q];
    a = fminf(fmaxf(a, 1.0f), L_CONST);
    out[q] = rep * a;
}

extern "C" void kernel_launch(void* const* d_in, const int* in_sizes, int n_in,
                              void* d_out, int out_size, void* d_ws, size_t ws_size,
                              hipStream_t stream) {
    const float* s   = (const float*)d_in[0];
    const float* w1  = (const float*)d_in[1];
    const float* b1  = (const float*)d_in[2];
    const float* w2  = (const float*)d_in[3];
    const float* b2  = (const float*)d_in[4];
    const float* w3  = (const float*)d_in[5];
    const float* b3  = (const float*)d_in[6];
    const float* wt1 = (const float*)d_in[7];
    const float* bt1 = (const float*)d_in[8];
    const float* wt2 = (const float*)d_in[9];
    const float* bt2 = (const float*)d_in[10];
    const float* wt3 = (const float*)d_in[11];
    const float* bt3 = (const float*)d_in[12];
    const float* wz1 = (const float*)d_in[13];
    const float* bz1 = (const float*)d_in[14];
    const float* wz2 = (const float*)d_in[15];
    const float* bz2 = (const float*)d_in[16];
    const float* wz3 = (const float*)d_in[17];
    const float* bz3 = (const float*)d_in[18];

    char* ws = (char*)d_ws;
    unsigned short* zb = (unsigned short*)(ws);            // 8192*128*2 = 2 MB
    float* sq    = (float*)(ws + 2097152);                  // 32 KB
    float* alpha = (float*)(ws + 2097152 + 32768);          // 32 KB
    float* part  = (float*)(ws + 2097152 + 65536);          // 8*8192*10*4 = 2.62 MB
    float* sumk  = (float*)(ws + 2097152 + 65536 + 2621440);
    float* total = (float*)(ws + 2097152 + 65536 + 2621440 + 32768);

    hipMemsetAsync(total, 0, sizeof(float), stream);

    k_mlp<<<512, 384, 0, stream>>>(s, w1, b1, w2, b2, w3, b3,
                                   wt1, bt1, wt2, bt2, wt3, bt3,
                                   wz1, bz1, wz2, bz2, wz3, bz3,
                                   zb, sq, alpha);
    k_pairs<<<512, 256, 0, stream>>>(zb, sq, part);
    k_merge<<<32, 256, 0, stream>>>(part, sq, sumk, total);
    k_final<<<32, 256, 0, stream>>>(sumk, alpha, total, (float*)d_out);
}

// Round 2
// 214.716 us; speedup vs baseline: 1.5727x; 1.5727x over previous
//
#include <hip/hip_runtime.h>
#include <hip/hip_bf16.h>

#define NROWS 8192
#define SD 512
#define FDIM 128
#define KNN 10
#define C_CONST 1.0e-3f
#define L_CONST 5.0f
#define EPS_CONST 1.0e-3f
#define BIGF 3.0e38f

typedef float f32x4 __attribute__((ext_vector_type(4)));
typedef __bf16 bf16x8 __attribute__((ext_vector_type(8)));
typedef unsigned short ushort4v __attribute__((ext_vector_type(4)));

union U8 { unsigned short u[8]; bf16x8 b; };

__device__ __forceinline__ unsigned short f32_to_bf16_rne(float f) {
    unsigned int x = __float_as_uint(f);
    unsigned int lsb = (x >> 16) & 1u;
    x += 0x7fffu + lsb;
    return (unsigned short)(x >> 16);
}

__device__ __forceinline__ void split_bf16(float v, unsigned short& h, unsigned short& l) {
    unsigned short hh = f32_to_bf16_rne(v);
    float hf = __uint_as_float(((unsigned int)hh) << 16);
    h = hh;
    l = f32_to_bf16_rne(v - hf);
}

// ---------------- K0: weight prep (concat + block-diag pad + hi/lo split) ----------------
__global__ __launch_bounds__(256) void k_prep(
    const float* __restrict__ w1, const float* __restrict__ wt1, const float* __restrict__ wz1,
    const float* __restrict__ w2, const float* __restrict__ wt2, const float* __restrict__ wz2,
    const float* __restrict__ w3, const float* __restrict__ wt3, const float* __restrict__ wz3,
    const float* __restrict__ b1, const float* __restrict__ bt1, const float* __restrict__ bz1,
    const float* __restrict__ b2, const float* __restrict__ bt2, const float* __restrict__ bz2,
    const float* __restrict__ b3, const float* __restrict__ bt3, const float* __restrict__ bz3,
    unsigned short* __restrict__ w1h, unsigned short* __restrict__ w1l,
    unsigned short* __restrict__ w2h, unsigned short* __restrict__ w2l,
    unsigned short* __restrict__ w3h, unsigned short* __restrict__ w3l,
    float* __restrict__ b1c, float* __restrict__ b2c, float* __restrict__ b3c)
{
    const int b = blockIdx.x;
    const int t = threadIdx.x;
    if (b < 192) {
        // W1cat [384][512] dense concat
        int idx = (b * 256 + t) * 4;
        int n = idx >> 9, k = idx & 511;
        const float* src = (n < 128) ? (w1 + (size_t)n * 512)
                         : (n < 256) ? (wt1 + (size_t)(n - 128) * 512)
                                     : (wz1 + (size_t)(n - 256) * 512);
        f32x4 v = *(const f32x4*)(src + k);
        ushort4v h, l;
        #pragma unroll
        for (int j = 0; j < 4; ++j) { unsigned short hh, ll; split_bf16(v[j], hh, ll); h[j] = hh; l[j] = ll; }
        *(ushort4v*)(w1h + idx) = h;
        *(ushort4v*)(w1l + idx) = l;
    } else if (b < 264) {
        // W2cat [192][384] block-diag
        int idx = ((b - 192) * 256 + t) * 4;
        int n = idx / 384, k = idx % 384;
        f32x4 v = {0.f, 0.f, 0.f, 0.f};
        if (n < 64)       { if (k < 128)            v = *(const f32x4*)(w2  + (size_t)n * 128 + k); }
        else if (n < 128) { if (k >= 128 && k < 256) v = *(const f32x4*)(wt2 + (size_t)(n - 64) * 128 + (k - 128)); }
        else              { if (k >= 256)            v = *(const f32x4*)(wz2 + (size_t)(n - 128) * 128 + (k - 256)); }
        ushort4v h, l;
        #pragma unroll
        for (int j = 0; j < 4; ++j) { unsigned short hh, ll; split_bf16(v[j], hh, ll); h[j] = hh; l[j] = ll; }
        *(ushort4v*)(w2h + idx) = h;
        *(ushort4v*)(w2l + idx) = l;
    } else if (b < 291) {
        // W3cat [144][192]: row0=w3(k<64), row1=wt3(64<=k<128), rows16..143=wz3(k>=128)
        int idx = ((b - 264) * 256 + t) * 4;
        int n = idx / 192, k = idx % 192;
        f32x4 v = {0.f, 0.f, 0.f, 0.f};
        if (n == 0)                 { if (k < 64)             v = *(const f32x4*)(w3 + k); }
        else if (n == 1)            { if (k >= 64 && k < 128) v = *(const f32x4*)(wt3 + (k - 64)); }
        else if (n >= 16 && n < 144){ if (k >= 128)           v = *(const f32x4*)(wz3 + (size_t)(n - 16) * 64 + (k - 128)); }
        ushort4v h, l;
        #pragma unroll
        for (int j = 0; j < 4; ++j) { unsigned short hh, ll; split_bf16(v[j], hh, ll); h[j] = hh; l[j] = ll; }
        *(ushort4v*)(w3h + idx) = h;
        *(ushort4v*)(w3l + idx) = l;
    } else {
        for (int i = t; i < 720; i += 256) {
            if (i < 384)      b1c[i] = (i < 128) ? b1[i] : (i < 256) ? bt1[i - 128] : bz1[i - 256];
            else if (i < 576) { int j = i - 384; b2c[j] = (j < 64) ? b2[j] : (j < 128) ? bt2[j - 64] : bz2[j - 128]; }
            else              { int j = i - 576; b3c[j] = (j == 0) ? b3[0] : (j == 1) ? bt3[0] : (j < 16) ? 0.f : bz3[j - 16]; }
        }
    }
}

// ---------------- GEMM1: h1 = relu(s @ W1cat^T + b1c), M=8192 N=384 K=512 ----------------
// 256 blocks x 512 thr. wave w: rows blk*32+(w>>2)*16, n-tiles (w&3)*6..+6
__global__ __launch_bounds__(512) void k_gemm1(
    const float* __restrict__ s, const unsigned short* __restrict__ wh,
    const unsigned short* __restrict__ wl, const float* __restrict__ bias,
    float* __restrict__ h1)
{
    const int t = threadIdx.x;
    const int lane = t & 63;
    const int w = t >> 6;
    const int l15 = lane & 15, lg = lane >> 4;
    const int m = blockIdx.x * 32 + (w >> 2) * 16 + l15;
    const int nbase = (w & 3) * 6;

    f32x4 acc[6];
    #pragma unroll
    for (int i = 0; i < 6; ++i) acc[i] = (f32x4){0.f, 0.f, 0.f, 0.f};

    const float* srow = s + (size_t)m * SD;
    for (int kt = 0; kt < 16; ++kt) {
        const int k0 = kt * 32 + lg * 8;
        f32x4 xa = *(const f32x4*)(srow + k0);
        f32x4 xb = *(const f32x4*)(srow + k0 + 4);
        U8 xh, xl;
        #pragma unroll
        for (int j = 0; j < 4; ++j) {
            split_bf16(xa[j], xh.u[j], xl.u[j]);
            split_bf16(xb[j], xh.u[4 + j], xl.u[4 + j]);
        }
        #pragma unroll
        for (int i = 0; i < 6; ++i) {
            const size_t off = (size_t)((nbase + i) * 16 + l15) * 512 + k0;
            bf16x8 bh = *(const bf16x8*)(wh + off);
            bf16x8 bl = *(const bf16x8*)(wl + off);
            acc[i] = __builtin_amdgcn_mfma_f32_16x16x32_bf16(bh, xh.b, acc[i], 0, 0, 0);
            acc[i] = __builtin_amdgcn_mfma_f32_16x16x32_bf16(bl, xh.b, acc[i], 0, 0, 0);
            acc[i] = __builtin_amdgcn_mfma_f32_16x16x32_bf16(bh, xl.b, acc[i], 0, 0, 0);
        }
    }
    #pragma unroll
    for (int i = 0; i < 6; ++i) {
        const int n0 = (nbase + i) * 16 + lg * 4;
        f32x4 bv = *(const f32x4*)(bias + n0);
        f32x4 v = acc[i] + bv;
        #pragma unroll
        for (int r = 0; r < 4; ++r) v[r] = fmaxf(v[r], 0.f);
        *(f32x4*)(h1 + (size_t)m * 384 + n0) = v;
    }
}

// ---------------- GEMM2: h2 = relu(h1 @ W2cat^T + b2c), M=8192 N=192 K=384 ----------------
__global__ __launch_bounds__(512) void k_gemm2(
    const float* __restrict__ h1, const unsigned short* __restrict__ wh,
    const unsigned short* __restrict__ wl, const float* __restrict__ bias,
    float* __restrict__ h2)
{
    const int t = threadIdx.x;
    const int lane = t & 63;
    const int w = t >> 6;
    const int l15 = lane & 15, lg = lane >> 4;
    const int m = blockIdx.x * 32 + (w >> 2) * 16 + l15;
    const int nbase = (w & 3) * 3;

    f32x4 acc[3];
    #pragma unroll
    for (int i = 0; i < 3; ++i) acc[i] = (f32x4){0.f, 0.f, 0.f, 0.f};

    const float* xrow = h1 + (size_t)m * 384;
    for (int kt = 0; kt < 12; ++kt) {
        const int k0 = kt * 32 + lg * 8;
        f32x4 xa = *(const f32x4*)(xrow + k0);
        f32x4 xb = *(const f32x4*)(xrow + k0 + 4);
        U8 xh, xl;
        #pragma unroll
        for (int j = 0; j < 4; ++j) {
            split_bf16(xa[j], xh.u[j], xl.u[j]);
            split_bf16(xb[j], xh.u[4 + j], xl.u[4 + j]);
        }
        #pragma unroll
        for (int i = 0; i < 3; ++i) {
            const size_t off = (size_t)((nbase + i) * 16 + l15) * 384 + k0;
            bf16x8 bh = *(const bf16x8*)(wh + off);
            bf16x8 bl = *(const bf16x8*)(wl + off);
            acc[i] = __builtin_amdgcn_mfma_f32_16x16x32_bf16(bh, xh.b, acc[i], 0, 0, 0);
            acc[i] = __builtin_amdgcn_mfma_f32_16x16x32_bf16(bl, xh.b, acc[i], 0, 0, 0);
            acc[i] = __builtin_amdgcn_mfma_f32_16x16x32_bf16(bh, xl.b, acc[i], 0, 0, 0);
        }
    }
    #pragma unroll
    for (int i = 0; i < 3; ++i) {
        const int n0 = (nbase + i) * 16 + lg * 4;
        f32x4 bv = *(const f32x4*)(bias + n0);
        f32x4 v = acc[i] + bv;
        #pragma unroll
        for (int r = 0; r < 4; ++r) v[r] = fmaxf(v[r], 0.f);
        *(f32x4*)(h2 + (size_t)m * 192 + n0) = v;
    }
}

// ---------------- GEMM3: out144 = h2 @ W3cat^T + b3c; epilogue builds zb/sq/alpha ----------------
// N=144 (n0=pred, n1=tgt, n16..143 = z cols 0..127)
__global__ __launch_bounds__(512) void k_gemm3(
    const float* __restrict__ h2, const unsigned short* __restrict__ wh,
    const unsigned short* __restrict__ wl, const float* __restrict__ bias,
    unsigned short* __restrict__ zb, float* __restrict__ sq, float* __restrict__ alpha)
{
    __shared__ float sred[2][4][16];
    const int t = threadIdx.x;
    const int lane = t & 63;
    const int w = t >> 6;
    const int l15 = lane & 15, lg = lane >> 4;
    const int half = w >> 2, wq = w & 3;
    const int m = blockIdx.x * 32 + half * 16 + l15;
    const int ntab0[4] = {0, 3, 5, 7};
    const int ncnt[4] = {3, 2, 2, 2};
    const int nb = ntab0[wq], nc = ncnt[wq];

    f32x4 acc[3];
    #pragma unroll
    for (int i = 0; i < 3; ++i) acc[i] = (f32x4){0.f, 0.f, 0.f, 0.f};

    const float* xrow = h2 + (size_t)m * 192;
    for (int kt = 0; kt < 6; ++kt) {
        const int k0 = kt * 32 + lg * 8;
        f32x4 xa = *(const f32x4*)(xrow + k0);
        f32x4 xb = *(const f32x4*)(xrow + k0 + 4);
        U8 xh, xl;
        #pragma unroll
        for (int j = 0; j < 4; ++j) {
            split_bf16(xa[j], xh.u[j], xl.u[j]);
            split_bf16(xb[j], xh.u[4 + j], xl.u[4 + j]);
        }
        #pragma unroll
        for (int i = 0; i < 3; ++i) {
            if (i < nc) {
                const size_t off = (size_t)((nb + i) * 16 + l15) * 192 + k0;
                bf16x8 bh = *(const bf16x8*)(wh + off);
                bf16x8 bl = *(const bf16x8*)(wl + off);
                acc[i] = __builtin_amdgcn_mfma_f32_16x16x32_bf16(bh, xh.b, acc[i], 0, 0, 0);
                acc[i] = __builtin_amdgcn_mfma_f32_16x16x32_bf16(bl, xh.b, acc[i], 0, 0, 0);
                acc[i] = __builtin_amdgcn_mfma_f32_16x16x32_bf16(bh, xl.b, acc[i], 0, 0, 0);
            }
        }
    }

    float ssq = 0.f;
    float pred = 0.f, tgt = 0.f;
    #pragma unroll
    for (int i = 0; i < 3; ++i) {
        if (i < nc) {
            const int ntg = nb + i;
            const int n0 = ntg * 16 + lg * 4;
            f32x4 bv = *(const f32x4*)(bias + n0);
            f32x4 v = acc[i] + bv;
            if (ntg == 0) {
                if (lg == 0) { pred = v.x; tgt = v.y; }
            } else {
                ushort4v zu;
                #pragma unroll
                for (int r = 0; r < 4; ++r) {
                    unsigned short us = f32_to_bf16_rne(v[r]);
                    float zf = __uint_as_float(((unsigned int)us) << 16);
                    ssq += zf * zf;
                    zu[r] = us;
                }
                *(ushort4v*)(zb + (size_t)m * FDIM + (ntg - 1) * 16 + lg * 4) = zu;
            }
        }
    }
    ssq += __shfl_xor(ssq, 16);
    ssq += __shfl_xor(ssq, 32);
    if (lg == 0) sred[half][wq][l15] = ssq;
    __syncthreads();
    if (t < 32) {
        int hh = t >> 4, ll = t & 15;
        sq[blockIdx.x * 32 + hh * 16 + ll] =
            sred[hh][0][ll] + sred[hh][1][ll] + sred[hh][2][ll] + sred[hh][3][ll];
    }
    if (wq == 0 && lg == 0) {
        float d = pred - tgt;
        alpha[m] = d * d;
    }
}

// ---------------- K2: pairwise dist + per-lane top-10 ----------------
__global__ __launch_bounds__(256) void k_pairs(
    const unsigned short* __restrict__ zb, const float* __restrict__ sq,
    float* __restrict__ part)
{
    const int lane = threadIdx.x & 63;
    const int wgid = blockIdx.x * 4 + (threadIdx.x >> 6);
    const int qg = wgid >> 3;
    const int split = wgid & 7;
    const int l15 = lane & 15, lg = lane >> 4;

    bf16x8 bq[2][4];
    int qid[2];
    #pragma unroll
    for (int qt = 0; qt < 2; ++qt) {
        qid[qt] = qg * 32 + qt * 16 + l15;
        #pragma unroll
        for (int kk = 0; kk < 4; ++kk)
            bq[qt][kk] = *(const bf16x8*)(zb + (size_t)qid[qt] * FDIM + kk * 32 + lg * 8);
    }
    float vals[2][10];
    #pragma unroll
    for (int qt = 0; qt < 2; ++qt)
        #pragma unroll
        for (int i = 0; i < 10; ++i) vals[qt][i] = BIGF;

    const int c0 = split * 1024;
    for (int tile = 0; tile < 64; ++tile) {
        const int j0 = c0 + tile * 16;
        bf16x8 av[4];
        #pragma unroll
        for (int kk = 0; kk < 4; ++kk)
            av[kk] = *(const bf16x8*)(zb + (size_t)(j0 + l15) * FDIM + kk * 32 + lg * 8);
        f32x4 sqv = *(const f32x4*)(sq + j0 + lg * 4);
        #pragma unroll
        for (int qt = 0; qt < 2; ++qt) {
            f32x4 acc = {0.f, 0.f, 0.f, 0.f};
            #pragma unroll
            for (int kk = 0; kk < 4; ++kk)
                acc = __builtin_amdgcn_mfma_f32_16x16x32_bf16(av[kk], bq[qt][kk], acc, 0, 0, 0);
            #pragma unroll
            for (int r = 0; r < 4; ++r) {
                int j = j0 + lg * 4 + r;
                float v = sqv[r] - 2.0f * acc[r];
                if (j == qid[qt]) v = BIGF;
                if (v < vals[qt][9]) {
                    float tv = v;
                    #pragma unroll
                    for (int s2 = 0; s2 < 10; ++s2) {
                        float lo = fminf(vals[qt][s2], tv);
                        tv = fmaxf(vals[qt][s2], tv);
                        vals[qt][s2] = lo;
                    }
                }
            }
        }
    }
    #pragma unroll
    for (int stage = 16; stage <= 32; stage <<= 1) {
        #pragma unroll
        for (int qt = 0; qt < 2; ++qt) {
            float other[10];
            #pragma unroll
            for (int s2 = 0; s2 < 10; ++s2) other[s2] = __shfl_xor(vals[qt][s2], stage, 64);
            #pragma unroll
            for (int s2 = 0; s2 < 10; ++s2) {
                float tv = other[s2];
                if (tv < vals[qt][9]) {
                    #pragma unroll
                    for (int u = 0; u < 10; ++u) {
                        float lo = fminf(vals[qt][u], tv);
                        tv = fmaxf(vals[qt][u], tv);
                        vals[qt][u] = lo;
                    }
                }
            }
        }
    }
    if (lg == 0) {
        #pragma unroll
        for (int qt = 0; qt < 2; ++qt) {
            float* dst = part + ((size_t)split * NROWS + qid[qt]) * KNN;
            #pragma unroll
            for (int s2 = 0; s2 < 10; ++s2) dst[s2] = vals[qt][s2];
        }
    }
}

// ---------------- K3: merge 8 partial lists ----------------
__global__ __launch_bounds__(256) void k_merge(
    const float* __restrict__ part, const float* __restrict__ sq,
    float* __restrict__ sumk, float* __restrict__ total)
{
    const int q = blockIdx.x * 256 + threadIdx.x;
    float vals[10];
    #pragma unroll
    for (int i = 0; i < 10; ++i) vals[i] = BIGF;
    for (int seg = 0; seg < 8; ++seg) {
        const float* p = part + ((size_t)seg * NROWS + q) * KNN;
        #pragma unroll
        for (int i = 0; i < 10; ++i) {
            float tv = p[i];
            if (tv < vals[9]) {
                #pragma unroll
                for (int u = 0; u < 10; ++u) {
                    float lo = fminf(vals[u], tv);
                    tv = fmaxf(vals[u], tv);
                    vals[u] = lo;
                }
            }
        }
    }
    float sqq = sq[q];
    float sum = 0.f;
    #pragma unroll
    for (int i = 0; i < 10; ++i) {
        float raw = sqq + vals[i];
        sum += (raw > 0.f) ? sqrtf(raw) : 0.f;
    }
    sumk[q] = sum;

    __shared__ float red[4];
    float bsum = sum;
    #pragma unroll
    for (int off = 32; off > 0; off >>= 1) bsum += __shfl_down(bsum, off);
    if ((threadIdx.x & 63) == 0) red[threadIdx.x >> 6] = bsum;
    __syncthreads();
    if (threadIdx.x == 0) atomicAdd(total, red[0] + red[1] + red[2] + red[3]);
}

// ---------------- K4: finalize ----------------
__global__ __launch_bounds__(256) void k_final(
    const float* __restrict__ sumk, const float* __restrict__ alpha,
    const float* __restrict__ total, float* __restrict__ out)
{
    const int q = blockIdx.x * 256 + threadIdx.x;
    float mean = (*total) * (1.0f / NROWS);
    float m2 = mean * mean;
    float sk = sumk[q];
    float x = (sk * sk) / m2;
    float knn = EPS_CONST / (x + EPS_CONST);
    float rep = 1.0f / (sqrtf(knn) + C_CONST);
    float a = alpha[q];
    a = fminf(fmaxf(a, 1.0f), L_CONST);
    out[q] = rep * a;
}

extern "C" void kernel_launch(void* const* d_in, const int* in_sizes, int n_in,
                              void* d_out, int out_size, void* d_ws, size_t ws_size,
                              hipStream_t stream) {
    const float* s   = (const float*)d_in[0];
    const float* w1  = (const float*)d_in[1];
    const float* b1  = (const float*)d_in[2];
    const float* w2  = (const float*)d_in[3];
    const float* b2  = (const float*)d_in[4];
    const float* w3  = (const float*)d_in[5];
    const float* b3  = (const float*)d_in[6];
    const float* wt1 = (const float*)d_in[7];
    const float* bt1 = (const float*)d_in[8];
    const float* wt2 = (const float*)d_in[9];
    const float* bt2 = (const float*)d_in[10];
    const float* wt3 = (const float*)d_in[11];
    const float* bt3 = (const float*)d_in[12];
    const float* wz1 = (const float*)d_in[13];
    const float* bz1 = (const float*)d_in[14];
    const float* wz2 = (const float*)d_in[15];
    const float* bz2 = (const float*)d_in[16];
    const float* wz3 = (const float*)d_in[17];
    const float* bz3 = (const float*)d_in[18];

    char* ws = (char*)d_ws;
    unsigned short* zb = (unsigned short*)(ws);                 // 2 MB
    float* sq    = (float*)(ws + 2097152);                      // 32 KB
    float* alpha = (float*)(ws + 2129920);                      // 32 KB
    float* part  = (float*)(ws + 2162688);                      // 2.62 MB
    float* sumk  = (float*)(ws + 4784128);                      // 32 KB
    float* total = (float*)(ws + 4816896);                      // 256 B pad
    float* h1    = (float*)(ws + 4817152);                      // 8192*384*4 = 12582912
    float* h2    = (float*)(ws + 17400064);                     // 8192*192*4 = 6291456
    unsigned short* w1h = (unsigned short*)(ws + 23691520);     // 393216
    unsigned short* w1l = (unsigned short*)(ws + 24084736);     // 393216
    unsigned short* w2h = (unsigned short*)(ws + 24477952);     // 147456
    unsigned short* w2l = (unsigned short*)(ws + 24625408);     // 147456
    unsigned short* w3h = (unsigned short*)(ws + 24772864);     // 55296
    unsigned short* w3l = (unsigned short*)(ws + 24828160);     // 55296
    float* b1c = (float*)(ws + 24883456);                       // 1536
    float* b2c = (float*)(ws + 24884992);                       // 768
    float* b3c = (float*)(ws + 24885760);                       // 576

    hipMemsetAsync(total, 0, sizeof(float), stream);

    k_prep<<<292, 256, 0, stream>>>(w1, wt1, wz1, w2, wt2, wz2, w3, wt3, wz3,
                                    b1, bt1, bz1, b2, bt2, bz2, b3, bt3, bz3,
                                    w1h, w1l, w2h, w2l, w3h, w3l, b1c, b2c, b3c);
    k_gemm1<<<256, 512, 0, stream>>>(s, w1h, w1l, b1c, h1);
    k_gemm2<<<256, 512, 0, stream>>>(h1, w2h, w2l, b2c, h2);
    k_gemm3<<<256, 512, 0, stream>>>(h2, w3h, w3l, b3c, zb, sq, alpha);
    k_pairs<<<512, 256, 0, stream>>>(zb, sq, part);
    k_merge<<<32, 256, 0, stream>>>(part, sq, sumk, total);
    k_final<<<32, 256, 0, stream>>>(sumk, alpha, total, (float*)d_out);
}

// Round 3
// 201.462 us; speedup vs baseline: 1.6761x; 1.0658x over previous
//
#include <hip/hip_runtime.h>
#include <hip/hip_bf16.h>

#define NROWS 8192
#define SD 512
#define FDIM 128
#define KNN 10
#define C_CONST 1.0e-3f
#define L_CONST 5.0f
#define EPS_CONST 1.0e-3f
#define BIGF 3.0e38f
#define BCAP 17
#define TRIG 12

typedef float f32x4 __attribute__((ext_vector_type(4)));
typedef __bf16 bf16x8 __attribute__((ext_vector_type(8)));
typedef unsigned short ushort4v __attribute__((ext_vector_type(4)));

union U8 { unsigned short u[8]; bf16x8 b; };

__device__ __forceinline__ unsigned short f32_to_bf16_rne(float f) {
    unsigned int x = __float_as_uint(f);
    unsigned int lsb = (x >> 16) & 1u;
    x += 0x7fffu + lsb;
    return (unsigned short)(x >> 16);
}

__device__ __forceinline__ void split_bf16(float v, unsigned short& h, unsigned short& l) {
    unsigned short hh = f32_to_bf16_rne(v);
    float hf = __uint_as_float(((unsigned int)hh) << 16);
    h = hh;
    l = f32_to_bf16_rne(v - hf);
}

// sorted ascending insert of one value into 10-reg list
__device__ __forceinline__ void insert10(float* vals, float tv) {
    #pragma unroll
    for (int u = 0; u < 10; ++u) {
        float lo = fminf(vals[u], tv);
        tv = fmaxf(vals[u], tv);
        vals[u] = lo;
    }
}

// fold LDS append-buffer into sorted-10 regs
__device__ __forceinline__ void compact16(float* vals, const float* bp, int cnt) {
    #pragma unroll
    for (int i = 0; i < 16; ++i) {
        float tv = (i < cnt) ? bp[i] : BIGF;
        insert10(vals, tv);
    }
}

__device__ __forceinline__ void ce(float& a, float& b) {
    float lo = fminf(a, b), hi = fmaxf(a, b); a = lo; b = hi;
}
// sort a bitonic (rise-then-fall) 10-seq ascending: clipped 16-bitonic-merge, 15 CE
__device__ __forceinline__ void sortBitonic10(float* w) {
    ce(w[0],w[8]); ce(w[1],w[9]);
    ce(w[2],w[6]); ce(w[3],w[7]); ce(w[4],w[8]); ce(w[5],w[9]);
    ce(w[2],w[4]); ce(w[3],w[5]); ce(w[6],w[8]); ce(w[7],w[9]);
    ce(w[0],w[1]); ce(w[2],w[3]); ce(w[4],w[5]); ce(w[6],w[7]); ce(w[8],w[9]);
}

// ---------------- K0: weight prep (concat + block-diag pad + hi/lo split) ----------------
__global__ __launch_bounds__(256) void k_prep(
    const float* __restrict__ w1, const float* __restrict__ wt1, const float* __restrict__ wz1,
    const float* __restrict__ w2, const float* __restrict__ wt2, const float* __restrict__ wz2,
    const float* __restrict__ w3, const float* __restrict__ wt3, const float* __restrict__ wz3,
    const float* __restrict__ b1, const float* __restrict__ bt1, const float* __restrict__ bz1,
    const float* __restrict__ b2, const float* __restrict__ bt2, const float* __restrict__ bz2,
    const float* __restrict__ b3, const float* __restrict__ bt3, const float* __restrict__ bz3,
    unsigned short* __restrict__ w1h, unsigned short* __restrict__ w1l,
    unsigned short* __restrict__ w2h, unsigned short* __restrict__ w2l,
    unsigned short* __restrict__ w3h, unsigned short* __restrict__ w3l,
    float* __restrict__ b1c, float* __restrict__ b2c, float* __restrict__ b3c)
{
    const int b = blockIdx.x;
    const int t = threadIdx.x;
    if (b < 192) {
        int idx = (b * 256 + t) * 4;
        int n = idx >> 9, k = idx & 511;
        const float* src = (n < 128) ? (w1 + (size_t)n * 512)
                         : (n < 256) ? (wt1 + (size_t)(n - 128) * 512)
                                     : (wz1 + (size_t)(n - 256) * 512);
        f32x4 v = *(const f32x4*)(src + k);
        ushort4v h, l;
        #pragma unroll
        for (int j = 0; j < 4; ++j) { unsigned short hh, ll; split_bf16(v[j], hh, ll); h[j] = hh; l[j] = ll; }
        *(ushort4v*)(w1h + idx) = h;
        *(ushort4v*)(w1l + idx) = l;
    } else if (b < 264) {
        int idx = ((b - 192) * 256 + t) * 4;
        int n = idx / 384, k = idx % 384;
        f32x4 v = {0.f, 0.f, 0.f, 0.f};
        if (n < 64)       { if (k < 128)             v = *(const f32x4*)(w2  + (size_t)n * 128 + k); }
        else if (n < 128) { if (k >= 128 && k < 256) v = *(const f32x4*)(wt2 + (size_t)(n - 64) * 128 + (k - 128)); }
        else              { if (k >= 256)            v = *(const f32x4*)(wz2 + (size_t)(n - 128) * 128 + (k - 256)); }
        ushort4v h, l;
        #pragma unroll
        for (int j = 0; j < 4; ++j) { unsigned short hh, ll; split_bf16(v[j], hh, ll); h[j] = hh; l[j] = ll; }
        *(ushort4v*)(w2h + idx) = h;
        *(ushort4v*)(w2l + idx) = l;
    } else if (b < 291) {
        int idx = ((b - 264) * 256 + t) * 4;
        int n = idx / 192, k = idx % 192;
        f32x4 v = {0.f, 0.f, 0.f, 0.f};
        if (n == 0)                 { if (k < 64)             v = *(const f32x4*)(w3 + k); }
        else if (n == 1)            { if (k >= 64 && k < 128) v = *(const f32x4*)(wt3 + (k - 64)); }
        else if (n >= 16 && n < 144){ if (k >= 128)           v = *(const f32x4*)(wz3 + (size_t)(n - 16) * 64 + (k - 128)); }
        ushort4v h, l;
        #pragma unroll
        for (int j = 0; j < 4; ++j) { unsigned short hh, ll; split_bf16(v[j], hh, ll); h[j] = hh; l[j] = ll; }
        *(ushort4v*)(w3h + idx) = h;
        *(ushort4v*)(w3l + idx) = l;
    } else {
        for (int i = t; i < 720; i += 256) {
            if (i < 384)      b1c[i] = (i < 128) ? b1[i] : (i < 256) ? bt1[i - 128] : bz1[i - 256];
            else if (i < 576) { int j = i - 384; b2c[j] = (j < 64) ? b2[j] : (j < 128) ? bt2[j - 64] : bz2[j - 128]; }
            else              { int j = i - 576; b3c[j] = (j == 0) ? b3[0] : (j == 1) ? bt3[0] : (j < 16) ? 0.f : bz3[j - 16]; }
        }
    }
}

// ---------------- GEMM1: h1 = relu(s @ W1cat^T + b1c) -> split bf16 hi/lo ----------------
__global__ __launch_bounds__(512, 2) void k_gemm1(
    const float* __restrict__ s, const unsigned short* __restrict__ wh,
    const unsigned short* __restrict__ wl, const float* __restrict__ bias,
    unsigned short* __restrict__ h1h, unsigned short* __restrict__ h1l)
{
    const int t = threadIdx.x;
    const int lane = t & 63;
    const int w = t >> 6;
    const int l15 = lane & 15, lg = lane >> 4;
    const int m = blockIdx.x * 32 + (w >> 2) * 16 + l15;
    const int nbase = (w & 3) * 6;

    f32x4 acc[6];
    #pragma unroll
    for (int i = 0; i < 6; ++i) acc[i] = (f32x4){0.f, 0.f, 0.f, 0.f};

    const float* srow = s + (size_t)m * SD;
    for (int kt = 0; kt < 16; ++kt) {
        const int k0 = kt * 32 + lg * 8;
        f32x4 xa = *(const f32x4*)(srow + k0);
        f32x4 xb = *(const f32x4*)(srow + k0 + 4);
        U8 xh, xl;
        #pragma unroll
        for (int j = 0; j < 4; ++j) {
            split_bf16(xa[j], xh.u[j], xl.u[j]);
            split_bf16(xb[j], xh.u[4 + j], xl.u[4 + j]);
        }
        #pragma unroll
        for (int i = 0; i < 6; ++i) {
            const size_t off = (size_t)((nbase + i) * 16 + l15) * 512 + k0;
            bf16x8 bh = *(const bf16x8*)(wh + off);
            bf16x8 bl = *(const bf16x8*)(wl + off);
            acc[i] = __builtin_amdgcn_mfma_f32_16x16x32_bf16(bh, xh.b, acc[i], 0, 0, 0);
            acc[i] = __builtin_amdgcn_mfma_f32_16x16x32_bf16(bl, xh.b, acc[i], 0, 0, 0);
            acc[i] = __builtin_amdgcn_mfma_f32_16x16x32_bf16(bh, xl.b, acc[i], 0, 0, 0);
        }
    }
    #pragma unroll
    for (int i = 0; i < 6; ++i) {
        const int n0 = (nbase + i) * 16 + lg * 4;
        f32x4 bv = *(const f32x4*)(bias + n0);
        f32x4 v = acc[i] + bv;
        ushort4v vh, vl;
        #pragma unroll
        for (int r = 0; r < 4; ++r) {
            float x = fmaxf(v[r], 0.f);
            unsigned short hh, ll; split_bf16(x, hh, ll);
            vh[r] = hh; vl[r] = ll;
        }
        *(ushort4v*)(h1h + (size_t)m * 384 + n0) = vh;
        *(ushort4v*)(h1l + (size_t)m * 384 + n0) = vl;
    }
}

// ---------------- GEMM2: h2 = relu(h1 @ W2cat^T + b2c) -> split bf16 hi/lo ----------------
__global__ __launch_bounds__(512, 2) void k_gemm2(
    const unsigned short* __restrict__ xh_, const unsigned short* __restrict__ xl_,
    const unsigned short* __restrict__ wh, const unsigned short* __restrict__ wl,
    const float* __restrict__ bias,
    unsigned short* __restrict__ h2h, unsigned short* __restrict__ h2l)
{
    const int t = threadIdx.x;
    const int lane = t & 63;
    const int w = t >> 6;
    const int l15 = lane & 15, lg = lane >> 4;
    const int m = blockIdx.x * 32 + (w >> 2) * 16 + l15;
    const int nbase = (w & 3) * 3;

    f32x4 acc[3];
    #pragma unroll
    for (int i = 0; i < 3; ++i) acc[i] = (f32x4){0.f, 0.f, 0.f, 0.f};

    const unsigned short* xh = xh_ + (size_t)m * 384;
    const unsigned short* xl = xl_ + (size_t)m * 384;
    for (int kt = 0; kt < 12; ++kt) {
        const int k0 = kt * 32 + lg * 8;
        bf16x8 axh = *(const bf16x8*)(xh + k0);
        bf16x8 axl = *(const bf16x8*)(xl + k0);
        #pragma unroll
        for (int i = 0; i < 3; ++i) {
            const size_t off = (size_t)((nbase + i) * 16 + l15) * 384 + k0;
            bf16x8 bh = *(const bf16x8*)(wh + off);
            bf16x8 bl = *(const bf16x8*)(wl + off);
            acc[i] = __builtin_amdgcn_mfma_f32_16x16x32_bf16(bh, axh, acc[i], 0, 0, 0);
            acc[i] = __builtin_amdgcn_mfma_f32_16x16x32_bf16(bl, axh, acc[i], 0, 0, 0);
            acc[i] = __builtin_amdgcn_mfma_f32_16x16x32_bf16(bh, axl, acc[i], 0, 0, 0);
        }
    }
    #pragma unroll
    for (int i = 0; i < 3; ++i) {
        const int n0 = (nbase + i) * 16 + lg * 4;
        f32x4 bv = *(const f32x4*)(bias + n0);
        f32x4 v = acc[i] + bv;
        ushort4v vh, vl;
        #pragma unroll
        for (int r = 0; r < 4; ++r) {
            float x = fmaxf(v[r], 0.f);
            unsigned short hh, ll; split_bf16(x, hh, ll);
            vh[r] = hh; vl[r] = ll;
        }
        *(ushort4v*)(h2h + (size_t)m * 192 + n0) = vh;
        *(ushort4v*)(h2l + (size_t)m * 192 + n0) = vl;
    }
}

// ---------------- GEMM3: out144 = h2 @ W3cat^T + b3c; epilogue builds zb/sq/alpha ----------------
__global__ __launch_bounds__(512, 2) void k_gemm3(
    const unsigned short* __restrict__ xh_, const unsigned short* __restrict__ xl_,
    const unsigned short* __restrict__ wh, const unsigned short* __restrict__ wl,
    const float* __restrict__ bias,
    unsigned short* __restrict__ zb, float* __restrict__ sq, float* __restrict__ alpha)
{
    __shared__ float sred[2][4][16];
    const int t = threadIdx.x;
    const int lane = t & 63;
    const int w = t >> 6;
    const int l15 = lane & 15, lg = lane >> 4;
    const int half = w >> 2, wq = w & 3;
    const int m = blockIdx.x * 32 + half * 16 + l15;
    const int nb = (wq == 0) ? 0 : (2 * wq + 1);   // 0,3,5,7
    const int nc = (wq == 0) ? 3 : 2;

    f32x4 acc[3];
    #pragma unroll
    for (int i = 0; i < 3; ++i) acc[i] = (f32x4){0.f, 0.f, 0.f, 0.f};

    const unsigned short* xh = xh_ + (size_t)m * 192;
    const unsigned short* xl = xl_ + (size_t)m * 192;
    for (int kt = 0; kt < 6; ++kt) {
        const int k0 = kt * 32 + lg * 8;
        bf16x8 axh = *(const bf16x8*)(xh + k0);
        bf16x8 axl = *(const bf16x8*)(xl + k0);
        #pragma unroll
        for (int i = 0; i < 3; ++i) {
            if (i < nc) {
                const size_t off = (size_t)((nb + i) * 16 + l15) * 192 + k0;
                bf16x8 bh = *(const bf16x8*)(wh + off);
                bf16x8 bl = *(const bf16x8*)(wl + off);
                acc[i] = __builtin_amdgcn_mfma_f32_16x16x32_bf16(bh, axh, acc[i], 0, 0, 0);
                acc[i] = __builtin_amdgcn_mfma_f32_16x16x32_bf16(bl, axh, acc[i], 0, 0, 0);
                acc[i] = __builtin_amdgcn_mfma_f32_16x16x32_bf16(bh, axl, acc[i], 0, 0, 0);
            }
        }
    }

    float ssq = 0.f;
    float pred = 0.f, tgt = 0.f;
    #pragma unroll
    for (int i = 0; i < 3; ++i) {
        if (i < nc) {
            const int ntg = nb + i;
            const int n0 = ntg * 16 + lg * 4;
            f32x4 bv = *(const f32x4*)(bias + n0);
            f32x4 v = acc[i] + bv;
            if (ntg == 0) {
                if (lg == 0) { pred = v.x; tgt = v.y; }
            } else {
                ushort4v zu;
                #pragma unroll
                for (int r = 0; r < 4; ++r) {
                    unsigned short us = f32_to_bf16_rne(v[r]);
                    float zf = __uint_as_float(((unsigned int)us) << 16);
                    ssq += zf * zf;
                    zu[r] = us;
                }
                *(ushort4v*)(zb + (size_t)m * FDIM + (ntg - 1) * 16 + lg * 4) = zu;
            }
        }
    }
    ssq += __shfl_xor(ssq, 16);
    ssq += __shfl_xor(ssq, 32);
    if (lg == 0) sred[half][wq][l15] = ssq;
    __syncthreads();
    if (t < 32) {
        int hh = t >> 4, ll = t & 15;
        sq[blockIdx.x * 32 + hh * 16 + ll] =
            sred[hh][0][ll] + sred[hh][1][ll] + sred[hh][2][ll] + sred[hh][3][ll];
    }
    if (wq == 0 && lg == 0) {
        float d = pred - tgt;
        alpha[m] = d * d;
    }
}

// ---------------- K2: pairwise + threshold-filtered top-10 (masked LDS append) ----------------
__global__ __launch_bounds__(256, 2) void k_pairs(
    const unsigned short* __restrict__ zb, const float* __restrict__ sq,
    float* __restrict__ part)
{
    __shared__ float buf[4][2][64][BCAP];   // 34816 B
    const int lane = threadIdx.x & 63;
    const int wv = threadIdx.x >> 6;
    const int wgid = blockIdx.x * 4 + wv;
    const int qg = wgid >> 3;
    const int split = wgid & 7;
    const int l15 = lane & 15, lg = lane >> 4;

    float* bp0 = &buf[wv][0][lane][0];
    float* bp1 = &buf[wv][1][lane][0];

    const int qid0 = qg * 32 + l15;
    const int qid1 = qg * 32 + 16 + l15;
    bf16x8 bq[2][4];
    #pragma unroll
    for (int kk = 0; kk < 4; ++kk) {
        bq[0][kk] = *(const bf16x8*)(zb + (size_t)qid0 * FDIM + kk * 32 + lg * 8);
        bq[1][kk] = *(const bf16x8*)(zb + (size_t)qid1 * FDIM + kk * 32 + lg * 8);
    }

    float vals[2][10];
    #pragma unroll
    for (int qt = 0; qt < 2; ++qt)
        #pragma unroll
        for (int i = 0; i < 10; ++i) vals[qt][i] = BIGF;
    float thr0 = BIGF, thr1 = BIGF;
    int cnt0 = 0, cnt1 = 0;

    const int c0 = split * 1024;
    for (int tile = 0; tile < 64; ++tile) {
        const int j0 = c0 + tile * 16;
        bf16x8 av[4];
        #pragma unroll
        for (int kk = 0; kk < 4; ++kk)
            av[kk] = *(const bf16x8*)(zb + (size_t)(j0 + l15) * FDIM + kk * 32 + lg * 8);
        f32x4 sqv = *(const f32x4*)(sq + j0 + lg * 4);

        f32x4 acc0 = {0.f, 0.f, 0.f, 0.f};
        f32x4 acc1 = {0.f, 0.f, 0.f, 0.f};
        #pragma unroll
        for (int kk = 0; kk < 4; ++kk) {
            acc0 = __builtin_amdgcn_mfma_f32_16x16x32_bf16(av[kk], bq[0][kk], acc0, 0, 0, 0);
            acc1 = __builtin_amdgcn_mfma_f32_16x16x32_bf16(av[kk], bq[1][kk], acc1, 0, 0, 0);
        }
        #pragma unroll
        for (int r = 0; r < 4; ++r) {
            const int j = j0 + lg * 4 + r;
            float v0 = fmaf(-2.0f, acc0[r], sqv[r]);     // key = dist^2 - sq_i
            int ok0 = (int)(v0 < thr0) & (int)(j != qid0);
            bp0[cnt0] = v0;                               // overwritten if !ok0
            cnt0 += ok0;
            float v1 = fmaf(-2.0f, acc1[r], sqv[r]);
            int ok1 = (int)(v1 < thr1) & (int)(j != qid1);
            bp1[cnt1] = v1;
            cnt1 += ok1;
        }
        if (__any(cnt0 >= TRIG)) { compact16(vals[0], bp0, cnt0); thr0 = vals[0][9]; cnt0 = 0; }
        if (__any(cnt1 >= TRIG)) { compact16(vals[1], bp1, cnt1); thr1 = vals[1][9]; cnt1 = 0; }
    }
    compact16(vals[0], bp0, cnt0);
    compact16(vals[1], bp1, cnt1);

    // merge lane-groups: ^16 (min-trick) -> bitonic resort -> ^32 (min-trick)
    #pragma unroll
    for (int qt = 0; qt < 2; ++qt) {
        float wk[10];
        #pragma unroll
        for (int i = 0; i < 10; ++i) {
            float o = __shfl_xor(vals[qt][9 - i], 16);
            wk[i] = fminf(vals[qt][i], o);
        }
        sortBitonic10(wk);
        float m1[10];
        #pragma unroll
        for (int i = 0; i < 10; ++i) {
            float o = __shfl_xor(wk[9 - i], 32);
            m1[i] = fminf(wk[i], o);
        }
        if (lg == 0) {
            const int qid = (qt == 0) ? qid0 : qid1;
            float* dst = part + ((size_t)split * NROWS + qid) * KNN;
            #pragma unroll
            for (int i = 0; i < 10; ++i) dst[i] = m1[i];
        }
    }
}

// ---------------- K3: merge 8 partial (unsorted) lists ----------------
__global__ __launch_bounds__(256) void k_merge(
    const float* __restrict__ part, const float* __restrict__ sq,
    float* __restrict__ sumk, float* __restrict__ total)
{
    const int q = blockIdx.x * 256 + threadIdx.x;
    float vals[10];
    #pragma unroll
    for (int i = 0; i < 10; ++i) vals[i] = BIGF;
    for (int seg = 0; seg < 8; ++seg) {
        const float* p = part + ((size_t)seg * NROWS + q) * KNN;
        #pragma unroll
        for (int i = 0; i < 10; ++i) {
            float tv = p[i];
            if (tv < vals[9]) insert10(vals, tv);
        }
    }
    float sqq = sq[q];
    float sum = 0.f;
    #pragma unroll
    for (int i = 0; i < 10; ++i) {
        float raw = sqq + vals[i];
        sum += (raw > 0.f) ? sqrtf(raw) : 0.f;
    }
    sumk[q] = sum;

    __shared__ float red[4];
    float bsum = sum;
    #pragma unroll
    for (int off = 32; off > 0; off >>= 1) bsum += __shfl_down(bsum, off);
    if ((threadIdx.x & 63) == 0) red[threadIdx.x >> 6] = bsum;
    __syncthreads();
    if (threadIdx.x == 0) atomicAdd(total, red[0] + red[1] + red[2] + red[3]);
}

// ---------------- K4: finalize ----------------
__global__ __launch_bounds__(256) void k_final(
    const float* __restrict__ sumk, const float* __restrict__ alpha,
    const float* __restrict__ total, float* __restrict__ out)
{
    const int q = blockIdx.x * 256 + threadIdx.x;
    float mean = (*total) * (1.0f / NROWS);
    float m2 = mean * mean;
    float sk = sumk[q];
    float x = (sk * sk) / m2;
    float knn = EPS_CONST / (x + EPS_CONST);
    float rep = 1.0f / (sqrtf(knn) + C_CONST);
    float a = alpha[q];
    a = fminf(fmaxf(a, 1.0f), L_CONST);
    out[q] = rep * a;
}

extern "C" void kernel_launch(void* const* d_in, const int* in_sizes, int n_in,
                              void* d_out, int out_size, void* d_ws, size_t ws_size,
                              hipStream_t stream) {
    const float* s   = (const float*)d_in[0];
    const float* w1  = (const float*)d_in[1];
    const float* b1  = (const float*)d_in[2];
    const float* w2  = (const float*)d_in[3];
    const float* b2  = (const float*)d_in[4];
    const float* w3  = (const float*)d_in[5];
    const float* b3  = (const float*)d_in[6];
    const float* wt1 = (const float*)d_in[7];
    const float* bt1 = (const float*)d_in[8];
    const float* wt2 = (const float*)d_in[9];
    const float* bt2 = (const float*)d_in[10];
    const float* wt3 = (const float*)d_in[11];
    const float* bt3 = (const float*)d_in[12];
    const float* wz1 = (const float*)d_in[13];
    const float* bz1 = (const float*)d_in[14];
    const float* wz2 = (const float*)d_in[15];
    const float* bz2 = (const float*)d_in[16];
    const float* wz3 = (const float*)d_in[17];
    const float* bz3 = (const float*)d_in[18];

    char* ws = (char*)d_ws;
    unsigned short* zb  = (unsigned short*)(ws);                // 2 MB
    float* sq    = (float*)(ws + 2097152);                      // 32 KB
    float* alpha = (float*)(ws + 2129920);                      // 32 KB
    float* part  = (float*)(ws + 2162688);                      // 2.62 MB
    float* sumk  = (float*)(ws + 4784128);                      // 32 KB
    float* total = (float*)(ws + 4816896);                      // 256 B
    unsigned short* h1h = (unsigned short*)(ws + 4817152);      // 6291456
    unsigned short* h1l = (unsigned short*)(ws + 11108608);     // 6291456
    unsigned short* h2h = (unsigned short*)(ws + 17400064);     // 3145728
    unsigned short* h2l = (unsigned short*)(ws + 20545792);     // 3145728
    unsigned short* w1h = (unsigned short*)(ws + 23691520);     // 393216
    unsigned short* w1l = (unsigned short*)(ws + 24084736);     // 393216
    unsigned short* w2h = (unsigned short*)(ws + 24477952);     // 147456
    unsigned short* w2l = (unsigned short*)(ws + 24625408);     // 147456
    unsigned short* w3h = (unsigned short*)(ws + 24772864);     // 55296
    unsigned short* w3l = (unsigned short*)(ws + 24828160);     // 55296
    float* b1c = (float*)(ws + 24883456);
    float* b2c = (float*)(ws + 24884992);
    float* b3c = (float*)(ws + 24885760);

    hipMemsetAsync(total, 0, sizeof(float), stream);

    k_prep<<<292, 256, 0, stream>>>(w1, wt1, wz1, w2, wt2, wz2, w3, wt3, wz3,
                                    b1, bt1, bz1, b2, bt2, bz2, b3, bt3, bz3,
                                    w1h, w1l, w2h, w2l, w3h, w3l, b1c, b2c, b3c);
    k_gemm1<<<256, 512, 0, stream>>>(s, w1h, w1l, b1c, h1h, h1l);
    k_gemm2<<<256, 512, 0, stream>>>(h1h, h1l, w2h, w2l, b2c, h2h, h2l);
    k_gemm3<<<256, 512, 0, stream>>>(h2h, h2l, w3h, w3l, b3c, zb, sq, alpha);
    k_pairs<<<512, 256, 0, stream>>>(zb, sq, part);
    k_merge<<<32, 256, 0, stream>>>(part, sq, sumk, total);
    k_final<<<32, 256, 0, stream>>>(sumk, alpha, total, (float*)d_out);
}